// Round 15
// baseline (496.061 us; speedup 1.0000x reference)
//
#include <hip/hip_runtime.h>
#include <hip/hip_bf16.h>
#include <math.h>

#define SLEN 2048
#define DIM 256
#define NB 4
#define NKF 24
#define NH 1024
#define NROW (NB*SLEN)          // 8192
#define NTOT (NB*SLEN*DIM)      // 2097152

#define BM 128
#define BN 256
#define BKK 32
#define PADK 40                 // padded LDS stride for generic (reg-staged) GEMMs

#define KG 3                    // conv k-group blocks
#define KPB 8                   // filters per conv block
#define VELEMS ((size_t)NKF*NB*DIM*SLEN)   // W buffer: 50,331,648 ushorts (100.7 MB)

typedef __attribute__((ext_vector_type(8))) short bf16x8;
typedef __attribute__((ext_vector_type(4))) float f32x4;

struct __align__(16) U4 { unsigned int a, b, c, d; };
struct __align__(8)  S4 { unsigned short x, y, z, w; };

__device__ __forceinline__ unsigned short f2b(float v){
    union { __hip_bfloat16 h; unsigned short u; } cv;
    cv.h = __float2bfloat16(v);
    return cv.u;
}
__device__ __forceinline__ float b2f(unsigned short s){
    union { __hip_bfloat16 h; unsigned short u; } cv;
    cv.u = s;
    return __bfloat162float(cv.h);
}

// async global->LDS, 16B per lane; LDS dest = wave-uniform base + lane*16
__device__ __forceinline__ void gl_lds(const unsigned short* g, unsigned short* l){
    __builtin_amdgcn_global_load_lds((const __attribute__((address_space(1))) void*)g,
                                     (__attribute__((address_space(3))) void*)l, 16, 0, 0);
}

// swizzled slot index within a conv subtile: rows x 4 k-slots of 16B, 2-way-max bank conflicts
__device__ __forceinline__ int swzS(int row, int g){
    return ((row >> 3) << 5) + (g << 3) + ((row & 7) ^ g);
}

// ---------------- merged prep kernel: rmsnorm + casts(Me/Mo) + transposes + buildM + toep ----------------
__global__ void k_prep(const float* __restrict__ x, const float* __restrict__ rmsw,
                       const float4* __restrict__ Mu, const float4* __restrict__ Mp,
                       const float4* __restrict__ Mm,
                       const float* __restrict__ w1, const float* __restrict__ vv,
                       const float* __restrict__ w2, const float* __restrict__ my,
                       const float* __restrict__ phi,
                       unsigned short* __restrict__ u_b,
                       S4* __restrict__ MuB, S4* __restrict__ MeB, S4* __restrict__ MoB,
                       unsigned short* __restrict__ w1T, unsigned short* __restrict__ vT,
                       unsigned short* __restrict__ w2T,
                       unsigned short* __restrict__ pw, unsigned short* __restrict__ pwTs,
                       unsigned short* __restrict__ Q, unsigned short* __restrict__ Tt){
    __shared__ float red[4];
    int bid = blockIdx.x, tix = threadIdx.x;
    if (bid < NROW){
        int row = bid, t = tix;
        float v = x[(size_t)row*DIM + t];
        float ss = v*v;
        #pragma unroll
        for (int o = 32; o > 0; o >>= 1) ss += __shfl_down(ss, o, 64);
        if ((t & 63) == 0) red[t >> 6] = ss;
        __syncthreads();
        float tot = red[0]+red[1]+red[2]+red[3];
        float sc = rsqrtf(tot * (1.0f/256.0f) + 1e-6f);
        u_b[(size_t)row*DIM + t] = f2b(v * sc * rmsw[t]);
        return;
    }
    bid -= NROW;
    if (bid < 192){
        int i = bid*256 + tix;
        float4 v = Mu[i];
        S4 p; p.x=f2b(v.x); p.y=f2b(v.y); p.z=f2b(v.z); p.w=f2b(v.w);
        MuB[i] = p; return;
    }
    bid -= 192;
    if (bid < 1536){
        int i = bid*256 + tix;
        float4 a = Mp[i], b = Mm[i];
        S4 p; p.x=f2b(a.x+b.x); p.y=f2b(a.y+b.y); p.z=f2b(a.z+b.z); p.w=f2b(a.w+b.w);
        MeB[i] = p; return;
    }
    bid -= 1536;
    if (bid < 1536){
        int i = bid*256 + tix;
        float4 a = Mp[i], b = Mm[i];
        S4 p; p.x=f2b(a.x-b.x); p.y=f2b(a.y-b.y); p.z=f2b(a.z-b.z); p.w=f2b(a.w-b.w);
        MoB[i] = p; return;
    }
    bid -= 1536;
    if (bid < 1024){
        int i = bid*256 + tix; int r = i >> 10, c = i & 1023;
        w1T[(size_t)c*DIM + r] = f2b(w1[i]); return;
    }
    bid -= 1024;
    if (bid < 1024){
        int i = bid*256 + tix; int r = i >> 10, c = i & 1023;
        vT[(size_t)c*DIM + r] = f2b(vv[i]); return;
    }
    bid -= 1024;
    if (bid < 1024){
        int i = bid*256 + tix; int r = i >> 8, c = i & 255;
        w2T[(size_t)c*NH + r] = f2b(w2[i]); return;
    }
    bid -= 1024;
    if (bid < 1024){
        int i = bid*256 + tix;
        int r = i >> 9, c = i & 511;
        float v;
        if (r < 256) v = (c < 256) ? my[r*256 + c] : my[256*256 + r*256 + (c - 256)];
        else         v = (c == r - 256) ? 1.0f : 0.0f;
        unsigned short bb = f2b(v);
        pw [262144 + (size_t)r*512 + c] = bb;
        pwTs[(size_t)c*512 + r] = bb;
        if (r < 256 && c < 256) Q[65536 + r*256 + c] = bb;
        return;
    }
    bid -= 1024;
    {
        int i = bid*256 + tix;
        int e   = (i & 7) * 4;
        int row = (i >> 3) & 127;
        int c   = (i >> 10) & 7;
        int rem = (i >> 13) & 15;
        int k   = i >> 17;
        int d0 = rem*128 + row - (c*32 + e);
        S4 p;
        p.x = (d0   >= 0) ? f2b(phi[(size_t)(d0  )*NKF + k]) : (unsigned short)0;
        p.y = (d0-1 >= 0) ? f2b(phi[(size_t)(d0-1)*NKF + k]) : (unsigned short)0;
        p.z = (d0-2 >= 0) ? f2b(phi[(size_t)(d0-2)*NKF + k]) : (unsigned short)0;
        p.w = (d0-3 >= 0) ? f2b(phi[(size_t)(d0-3)*NKF + k]) : (unsigned short)0;
        size_t base = ((size_t)((k*16 + rem)*8 + c)) * 4096;
        *(S4*)&Tt[base + swzS(row, e>>3)*8 + (e&7)] = p;
    }
}

// out = y (f32 copy) and ybf = bf16(y)
__global__ void k_prep2(const float4* __restrict__ y, float4* __restrict__ out, S4* __restrict__ ybf){
    int i = blockIdx.x*256 + threadIdx.x;
    if (i < NTOT/4){
        float4 v = y[i];
        out[i] = v;
        S4 p; p.x=f2b(v.x); p.y=f2b(v.y); p.z=f2b(v.z); p.w=f2b(v.w);
        ybf[i] = p;
    }
}

// obf = bf16(out)
__global__ void k_cast_out(const float4* __restrict__ out, S4* __restrict__ obf){
    int i = blockIdx.x*256 + threadIdx.x;
    if (i < NTOT/4){
        float4 v = out[i];
        S4 p; p.x=f2b(v.x); p.y=f2b(v.y); p.z=f2b(v.z); p.w=f2b(v.w);
        obf[i] = p;
    }
}

// ---------------- shared MFMA tile core (generic reg-staged GEMMs) ----------------

__device__ __forceinline__ void mfma_tile(const unsigned short* Al, const unsigned short* Bl,
                                          f32x4 acc[4][4], int lane, int wr, int wc){
    int cl = lane & 15;
    int kb = (lane >> 4) * 8;
    bf16x8 a[4], b[4];
    #pragma unroll
    for (int mi = 0; mi < 4; ++mi)
        a[mi] = *(const bf16x8*)&Al[(wr*64 + mi*16 + cl)*PADK + kb];
    #pragma unroll
    for (int ni = 0; ni < 4; ++ni)
        b[ni] = *(const bf16x8*)&Bl[(wc*64 + ni*16 + cl)*PADK + kb];
    #pragma unroll
    for (int mi = 0; mi < 4; ++mi)
        #pragma unroll
        for (int ni = 0; ni < 4; ++ni)
            acc[mi][ni] = __builtin_amdgcn_mfma_f32_16x16x32_bf16(a[mi], b[ni], acc[mi][ni], 0, 0, 0);
}

#define GEMM_PROLOG \
    __shared__ unsigned short Al[BM*PADK]; \
    __shared__ unsigned short Bl[BN*PADK]; \
    int tid = threadIdx.x, lane = tid & 63, wv = tid >> 6, wr = wv >> 2, wc = wv & 3; \
    f32x4 acc[4][4]; \
    { f32x4 z = {0.f,0.f,0.f,0.f}; \
      for (int mi=0;mi<4;++mi) for (int ni=0;ni<4;++ni) acc[mi][ni] = z; }

// ---------------- power doubling (P=8 chain): M^(ns+j) = M^j * M^ns ----------------
__global__ __launch_bounds__(512) void k_pow(unsigned short* __restrict__ pw, unsigned short* __restrict__ pwTs,
                                             unsigned short* __restrict__ Q, int s, int ns){
    int mt = blockIdx.x, nt = blockIdx.y;
    int j = 1 + blockIdx.z;
    int p = ns + j;
    int m0 = mt * BM, n0 = nt * BN;
    int fullNeed = (p <= 3) || (j == ns && ns <= 2);
    if (!fullNeed && (m0 >= 256 || n0 >= 256)) return;
    GEMM_PROLOG
    const unsigned short* A = pw   + (size_t)j * 262144;
    const unsigned short* B = pwTs + (size_t)s * 262144;
    for (int k0 = 0; k0 < 512; k0 += BKK){
        __syncthreads();
        { int row = tid >> 2, sg = tid & 3;
          *(U4*)&Al[row*PADK + sg*8] = *(const U4*)&A[(size_t)(m0+row)*512 + k0 + sg*8]; }
        #pragma unroll
        for (int ss = 0; ss < 2; ++ss){ int q = tid + ss*512; int row = q >> 2, sg = q & 3;
          *(U4*)&Bl[row*PADK + sg*8] = *(const U4*)&B[(size_t)(n0+row)*512 + k0 + sg*8]; }
        __syncthreads();
        mfma_tile(Al, Bl, acc, lane, wr, wc);
    }
    int cl = lane & 15, rg = (lane >> 4) * 4;
    #pragma unroll
    for (int mi=0; mi<4; ++mi){
        int rb = m0 + wr*64 + mi*16 + rg;
        #pragma unroll
        for (int ni=0; ni<4; ++ni){
            int col = n0 + wc*64 + ni*16 + cl;
            unsigned short bb[4];
            #pragma unroll
            for (int r=0;r<4;++r) bb[r] = f2b(acc[mi][ni][r]);
            if (p <= 3){
                #pragma unroll
                for (int r=0;r<4;++r) pw[(size_t)p*262144 + (size_t)(rb+r)*512 + col] = bb[r];
            }
            if (j == ns && ns <= 2){
                S4 pk; pk.x=bb[0]; pk.y=bb[1]; pk.z=bb[2]; pk.w=bb[3];
                *(S4*)&pwTs[(size_t)(s+1)*262144 + (size_t)col*512 + rb] = pk;
            }
            if (rb < 256 && col < 256 && p <= 7){
                #pragma unroll
                for (int r=0;r<4;++r) Q[(size_t)p*65536 + (size_t)(rb+r)*256 + col] = bb[r];
            }
        }
    }
}

// ---------------- ar_u: y = sum_i shift(u,i) @ M_u[i]^T ----------------
__global__ __launch_bounds__(512) void k_aru(const unsigned short* __restrict__ u,
                                             const unsigned short* __restrict__ Mu, float* __restrict__ y){
    GEMM_PROLOG
    int tt = blockIdx.x, b = blockIdx.y;
    int t0 = tt * BM;
    const unsigned short* Ab = u + (size_t)b*SLEN*DIM;
    for (int i = 0; i < 3; ++i){
        const unsigned short* Bsrc = Mu + (size_t)i*65536;
        for (int k0 = 0; k0 < 256; k0 += BKK){
            __syncthreads();
            { int row = tid >> 2, sg = tid & 3; int t = t0 + row - i;
              U4 val; val.a=val.b=val.c=val.d=0u;
              if (t >= 0) val = *(const U4*)&Ab[(size_t)t*DIM + k0 + sg*8];
              *(U4*)&Al[row*PADK + sg*8] = val; }
            #pragma unroll
            for (int s = 0; s < 2; ++s){ int q = tid + s*512; int row = q >> 2, sg = q & 3;
              *(U4*)&Bl[row*PADK + sg*8] = *(const U4*)&Bsrc[(size_t)row*DIM + k0 + sg*8]; }
            __syncthreads();
            mfma_tile(Al, Bl, acc, lane, wr, wc);
        }
    }
    int cl = lane & 15, rg = (lane >> 4) * 4;
    #pragma unroll
    for (int mi=0; mi<4; ++mi){
        int tb = t0 + wr*64 + mi*16 + rg;
        #pragma unroll
        for (int ni=0; ni<4; ++ni){
            int o = wc*64 + ni*16 + cl;
            #pragma unroll
            for (int r=0;r<4;++r) y[((size_t)b*SLEN + tb + r)*DIM + o] = acc[mi][ni][r];
        }
    }
}

// ---------------- projection v5 (parity-split, paired-phase epilogue) ----------------
__global__ __launch_bounds__(512) void k_proj(const unsigned short* __restrict__ u,
                                              const unsigned short* __restrict__ Me,
                                              const unsigned short* __restrict__ Mo,
                                              const float* __restrict__ sigma,
                                              unsigned short* __restrict__ V){
    __shared__ unsigned short Al[BM*PADK];
    __shared__ unsigned short Bl0[BN*PADK];
    __shared__ unsigned short Bl1[BN*PADK];
    int tid = threadIdx.x, lane = tid & 63, wv = tid >> 6, wr = wv >> 2, wc = wv & 3;
    f32x4 acc[4][4];
    { f32x4 z = {0.f,0.f,0.f,0.f};
      for (int mi=0;mi<4;++mi) for (int ni=0;ni<4;++ni) acc[mi][ni] = z; }
    int tt = blockIdx.x, b = blockIdx.y, k = blockIdx.z;
    int t0 = tt * BM;
    float sr = powf(sigma[k], 0.25f);
    const unsigned short* Asrc  = u + ((size_t)b*SLEN)*DIM;
    const unsigned short* B0src = Me + (size_t)k*65536;
    const unsigned short* B1src = Mo + (size_t)k*65536;
    for (int k0 = 0; k0 < 256; k0 += BKK){
        __syncthreads();
        { int row = tid >> 2, sg = tid & 3;
          int t = (row < 64) ? (t0 + 2*row) : (t0 + 2*(row-64) + 1);
          *(U4*)&Al[row*PADK + sg*8] = *(const U4*)&Asrc[(size_t)t*DIM + k0 + sg*8]; }
        #pragma unroll
        for (int s = 0; s < 2; ++s){ int q = tid + s*512; int row = q >> 2, sg = q & 3;
          *(U4*)&Bl0[row*PADK + sg*8] = *(const U4*)&B0src[(size_t)row*DIM + k0 + sg*8];
          *(U4*)&Bl1[row*PADK + sg*8] = *(const U4*)&B1src[(size_t)row*DIM + k0 + sg*8]; }
        __syncthreads();
        mfma_tile(Al, wr ? Bl1 : Bl0, acc, lane, wr, wc);
    }
    int cl = lane & 15, rg = (lane >> 4) * 4;
    const int TRS = 136;
    #pragma unroll
    for (int h = 0; h < 2; ++h){
        __syncthreads();
        if ((wc >> 1) == h){
            unsigned short* Trm = (wc & 1) ? Bl1 : Bl0;
            #pragma unroll
            for (int mi=0; mi<4; ++mi){
                #pragma unroll
                for (int ni=0; ni<4; ++ni){
                    int ol = ni*16 + cl;
                    S4 pk;
                    pk.x = f2b(sr*acc[mi][ni][0]); pk.y = f2b(sr*acc[mi][ni][1]);
                    pk.z = f2b(sr*acc[mi][ni][2]); pk.w = f2b(sr*acc[mi][ni][3]);
                    #pragma unroll
                    for (int r=0; r<4; ++r){
                        int lr = mi*16 + rg + r;
                        int dt = wr ? (2*lr + 1) : (2*lr);
                        Trm[ol*TRS + dt] = (&pk.x)[r];
                    }
                }
            }
        }
        __syncthreads();
        { int row = tid >> 3, seg = tid & 7;
          int tb = (t0 >> 5) + (seg >> 1);
          int g0 = (seg & 1) * 2;
          size_t sb = ((size_t)(k*NB + b)*64 + tb) * 8192;
          #pragma unroll
          for (int q = 0; q < 2; ++q){
              const unsigned short* Trm = q ? Bl1 : Bl0;
              U4 v0 = *(const U4*)&Trm[row*TRS + seg*16];
              U4 v1 = *(const U4*)&Trm[row*TRS + seg*16 + 8];
              int o  = (2*h + q)*64 + row;
              *(U4*)&V[sb + swzS(o, g0  )*8] = v0;
              *(U4*)&V[sb + swzS(o, g0+1)*8] = v1;
          }
        }
    }
}

// ---------------- causal Toeplitz conv v10: 4 waves, wave tile 64x128 (acc[4][8]) ----------------
// reads/MFMA 0.5 -> 0.375 frags (LDS-BW bound per round-14 model). 3-buffer depth-2, vmcnt(6).
__global__ __launch_bounds__(256) void k_conv(const unsigned short* __restrict__ V,
                                              const unsigned short* __restrict__ Tt,
                                              float* __restrict__ y){
    __shared__ __align__(16) unsigned short Abuf[3][4096];   // 3x8KB
    __shared__ __align__(16) unsigned short Bbuf[3][8192];   // 3x16KB
    int tid = threadIdx.x, lane = tid & 63, wv = tid >> 6;   // wv 0..3
    int wr = wv >> 1, wc = wv & 1;                           // 2m x 2n wave grid
    f32x4 acc[4][8];
    { f32x4 z = {0.f,0.f,0.f,0.f};
      for (int mi=0;mi<4;++mi) for (int ni=0;ni<8;++ni) acc[mi][ni] = z; }

    int b = blockIdx.y, kg = blockIdx.z;
    int px0 = blockIdx.x;
    int px = (px0 & 7)*9 + (px0 >> 3);     // XCD-chunked swizzle (72 = 8 XCDs x 9)
    int jx = 0, rem = px;
    #pragma unroll
    for (int j = 0; j < 8; ++j){
        int c = 16 - 2*j;
        if (rem < c){ jx = j; break; }
        rem -= c;
    }
    int tt = 2*jx + rem;
    int t0 = tt*BM;
    int cl = lane & 15, g = lane >> 4;

    int aoff[4], boff[8];
    #pragma unroll
    for (int mi = 0; mi < 4; ++mi) aoff[mi] = swzS(wr*64 + mi*16 + cl, g) << 4;
    #pragma unroll
    for (int ni = 0; ni < 8; ++ni) boff[ni] = swzS(wc*128 + ni*16 + cl, g) << 4;

    const unsigned short* Abase = Tt + (size_t)((kg*KPB*16 + rem)*8) * 4096;
    const unsigned short* Bbase = V  + (((size_t)(kg*KPB*NB + b)*64 + jx*8)) * 8192;

    auto stage = [&](int bi, int step){   // 6 gl_lds per lane per tile
        int kk = step >> 3, ts = step & 7;
        const unsigned short* As = Abase + ((size_t)kk*16*8 + ts)*4096 + wv*1024;
        const unsigned short* Bs = Bbase + ((size_t)kk*NB*64 + ts)*8192 + wv*2048;
        gl_lds(As + lane*8,        &Abuf[bi][wv*1024]);
        gl_lds(As + 512 + lane*8,  &Abuf[bi][wv*1024 + 512]);
        gl_lds(Bs + lane*8,        &Bbuf[bi][wv*2048]);
        gl_lds(Bs + 512 + lane*8,  &Bbuf[bi][wv*2048 + 512]);
        gl_lds(Bs + 1024 + lane*8, &Bbuf[bi][wv*2048 + 1024]);
        gl_lds(Bs + 1536 + lane*8, &Bbuf[bi][wv*2048 + 1536]);
    };

    auto compute = [&](int bi){
        bf16x8 a[4], bb[8];
        #pragma unroll
        for (int mi = 0; mi < 4; ++mi)
            a[mi] = *(const bf16x8*)((const char*)Abuf[bi] + aoff[mi]);
        #pragma unroll
        for (int ni = 0; ni < 8; ++ni)
            bb[ni] = *(const bf16x8*)((const char*)Bbuf[bi] + boff[ni]);
        #pragma unroll
        for (int mi = 0; mi < 4; ++mi)
            #pragma unroll
            for (int ni = 0; ni < 8; ++ni)
                acc[mi][ni] = __builtin_amdgcn_mfma_f32_16x16x32_bf16(a[mi], bb[ni], acc[mi][ni], 0, 0, 0);
    };

    stage(0, 0);
    stage(1, 1);
    int cur = 0;
    for (int t = 0; t < KPB*8 - 1; ++t){
        asm volatile("s_waitcnt vmcnt(6)" ::: "memory");   // tile t's 6 loads retired; t+1's in flight
        __builtin_amdgcn_s_barrier();
        __builtin_amdgcn_sched_barrier(0);
        compute(cur);
        if (t + 2 < KPB*8){
            int nb = cur + 2; if (nb >= 3) nb -= 3;
            stage(nb, t + 2);
        }
        cur = (cur == 2) ? 0 : cur + 1;
    }
    asm volatile("s_waitcnt vmcnt(0)" ::: "memory");
    __builtin_amdgcn_s_barrier();
    __builtin_amdgcn_sched_barrier(0);
    compute(cur);

    int rg = (lane >> 4) * 4;
    #pragma unroll
    for (int mi=0; mi<4; ++mi){
        int tb = t0 + wr*64 + mi*16 + rg;
        #pragma unroll
        for (int ni=0; ni<8; ++ni){
            int o = wc*128 + ni*16 + cl;
            #pragma unroll
            for (int r=0;r<4;++r) atomicAdd(&y[((size_t)b*SLEN + tb + r)*DIM + o], acc[mi][ni][r]);
        }
    }
}

// ---------------- output AR via truncated Q-filter (P=8): gz=7, one tap per block ----------------
__global__ __launch_bounds__(512) void k_qconv(const unsigned short* __restrict__ ybf,
                                               const unsigned short* __restrict__ Q,
                                               float* __restrict__ yh){
    GEMM_PROLOG
    int tt = blockIdx.x, b = blockIdx.y, gz = blockIdx.z;
    int t0 = tt * BM;
    const unsigned short* ysrc = ybf + (size_t)b*SLEN*DIM;
    int p = gz + 1;                        // 1..7
    const unsigned short* Qp = Q + (size_t)p*65536;
    for (int k0 = 0; k0 < 256; k0 += BKK){
        __syncthreads();
        { int row = tid >> 2, sg = tid & 3; int t = t0 + row - p;
          U4 val; val.a=val.b=val.c=val.d=0u;
          if (t >= 0) val = *(const U4*)&ysrc[(size_t)t*DIM + k0 + sg*8];
          *(U4*)&Al[row*PADK + sg*8] = val; }
        #pragma unroll
        for (int s = 0; s < 2; ++s){ int q = tid + s*512; int row = q >> 2, sg = q & 3;
          *(U4*)&Bl[row*PADK + sg*8] = *(const U4*)&Qp[(size_t)row*256 + k0 + sg*8]; }
        __syncthreads();
        mfma_tile(Al, Bl, acc, lane, wr, wc);
    }
    int cl = lane & 15, rg = (lane >> 4) * 4;
    #pragma unroll
    for (int mi=0; mi<4; ++mi){
        int tb = t0 + wr*64 + mi*16 + rg;
        #pragma unroll
        for (int ni=0; ni<4; ++ni){
            int o = wc*64 + ni*16 + cl;
            #pragma unroll
            for (int r=0;r<4;++r) atomicAdd(&yh[((size_t)b*SLEN + tb + r)*DIM + o], acc[mi][ni][r]);
        }
    }
}

// ---------------- fused MLP GEMM1 (bf16 A): act = silu(.@w1)*(.@v) ----------------
__global__ __launch_bounds__(512) void k_mlp1f(const unsigned short* __restrict__ obf,
                                               const unsigned short* __restrict__ w1T,
                                               const unsigned short* __restrict__ vT,
                                               unsigned short* __restrict__ act){
    __shared__ unsigned short Al[BM*PADK];
    __shared__ unsigned short Bl0[BN*PADK];
    __shared__ unsigned short Bl1[BN*PADK];
    int tid = threadIdx.x, lane = tid & 63, wv = tid >> 6, wr = wv >> 2, wc = wv & 3;
    f32x4 acc0[4][4], acc1[4][4];
    { f32x4 z = {0.f,0.f,0.f,0.f};
      for (int mi=0;mi<4;++mi) for (int ni=0;ni<4;++ni){ acc0[mi][ni] = z; acc1[mi][ni] = z; } }
    int tt = blockIdx.x, b = blockIdx.y, nt = blockIdx.z;
    int t0 = tt * BM, h0 = nt * 256;
    const unsigned short* Asrc = obf + ((size_t)b*SLEN + t0)*DIM;
    const unsigned short* B0src = w1T + (size_t)h0*DIM;
    const unsigned short* B1src = vT  + (size_t)h0*DIM;
    for (int k0 = 0; k0 < 256; k0 += BKK){
        __syncthreads();
        { int row = tid >> 2, sg = tid & 3;
          *(U4*)&Al[row*PADK + sg*8] = *(const U4*)&Asrc[(size_t)row*DIM + k0 + sg*8]; }
        #pragma unroll
        for (int s = 0; s < 2; ++s){ int q = tid + s*512; int row = q >> 2, sg = q & 3;
          *(U4*)&Bl0[row*PADK + sg*8] = *(const U4*)&B0src[(size_t)row*DIM + k0 + sg*8];
          *(U4*)&Bl1[row*PADK + sg*8] = *(const U4*)&B1src[(size_t)row*DIM + k0 + sg*8]; }
        __syncthreads();
        mfma_tile(Al, Bl0, acc0, lane, wr, wc);
        mfma_tile(Al, Bl1, acc1, lane, wr, wc);
    }
    int cl = lane & 15, rg = (lane >> 4) * 4;
    #pragma unroll
    for (int mi=0; mi<4; ++mi){
        int tb = t0 + wr*64 + mi*16 + rg;
        #pragma unroll
        for (int ni=0; ni<4; ++ni){
            int h = h0 + wc*64 + ni*16 + cl;
            #pragma unroll
            for (int r=0; r<4; ++r){
                float av = acc0[mi][ni][r];
                float sv = av / (1.0f + expf(-av));
                act[(size_t)(b*SLEN + tb + r)*NH + h] = f2b(sv * acc1[mi][ni][r]);
            }
        }
    }
}

// ---------------- MLP GEMM2 (K split z=4): out(=yhat) += act@w2 partial + (z==0)*x ----------------
__global__ __launch_bounds__(512) void k_mlp2(const unsigned short* __restrict__ act,
                                              const unsigned short* __restrict__ w2T,
                                              const float* __restrict__ x,
                                              float* __restrict__ out){
    GEMM_PROLOG
    int tt = blockIdx.x, b = blockIdx.y, ks = blockIdx.z;
    int t0 = tt * BM;
    size_t bt0 = (size_t)b*SLEN + t0;
    for (int k0 = ks*256; k0 < ks*256 + 256; k0 += BKK){
        __syncthreads();
        { int row = tid >> 2, sg = tid & 3;
          *(U4*)&Al[row*PADK + sg*8] = *(const U4*)&act[(bt0 + row)*NH + k0 + sg*8]; }
        #pragma unroll
        for (int s = 0; s < 2; ++s){ int q = tid + s*512; int row = q >> 2, sg = q & 3;
          *(U4*)&Bl[row*PADK + sg*8] = *(const U4*)&w2T[(size_t)row*NH + k0 + sg*8]; }
        __syncthreads();
        mfma_tile(Al, Bl, acc, lane, wr, wc);
    }
    int cl = lane & 15, rg = (lane >> 4) * 4;
    #pragma unroll
    for (int mi=0; mi<4; ++mi){
        #pragma unroll
        for (int ni=0; ni<4; ++ni){
            int o = wc*64 + ni*16 + cl;
            #pragma unroll
            for (int r=0;r<4;++r){
                size_t idx = (bt0 + wr*64 + mi*16 + rg + r)*DIM + o;
                float add = acc[mi][ni][r] + (ks == 0 ? x[idx] : 0.0f);
                atomicAdd(&out[idx], add);
            }
        }
    }
}

// ---------------- host ----------------

extern "C" void kernel_launch(void* const* d_in, const int* in_sizes, int n_in,
                              void* d_out, int out_size, void* d_ws, size_t ws_size,
                              hipStream_t stream) {
    (void)in_sizes; (void)n_in; (void)out_size;
    const float* x     = (const float*)d_in[0];
    const float* sigma = (const float*)d_in[1];
    const float* phi   = (const float*)d_in[2];
    const float* rmsw  = (const float*)d_in[3];
    const float* Mu    = (const float*)d_in[4];
    const float* Mp    = (const float*)d_in[5];
    const float* Mm    = (const float*)d_in[6];
    const float* my    = (const float*)d_in[7];
    const float* w1    = (const float*)d_in[8];
    const float* vv    = (const float*)d_in[9];
    const float* w2    = (const float*)d_in[10];
    float* out = (float*)d_out;

    char* ws = (char*)d_ws;
    size_t off = 0;
    auto alloc = [&](size_t bytes){ size_t o = off; off += (bytes + 255) & ~(size_t)255; return o; };

    size_t o_u    = alloc((size_t)NROW*DIM*2);
    size_t o_T    = alloc((size_t)NKF*16*128*256*2);
    size_t o_MuB  = alloc((size_t)3*65536*2);
    size_t o_MeB  = alloc((size_t)NKF*65536*2);
    size_t o_MoB  = alloc((size_t)NKF*65536*2);
    size_t o_w1T  = alloc((size_t)NH*DIM*2);
    size_t o_vT   = alloc((size_t)NH*DIM*2);
    size_t o_w2T  = alloc((size_t)DIM*NH*2);
    size_t o_pow  = alloc((size_t)5*262144*2);
    size_t o_powT = alloc((size_t)3*262144*2);
    size_t o_Q    = alloc((size_t)8*65536*2);
    size_t o_y    = alloc((size_t)NTOT*4);
    size_t o_ybf  = alloc((size_t)NTOT*2);
    size_t o_V    = alloc(VELEMS*2);
    if (off > ws_size) return;

    unsigned short* u_b  = (unsigned short*)(ws + o_u);
    unsigned short* Tt   = (unsigned short*)(ws + o_T);
    unsigned short* MuB  = (unsigned short*)(ws + o_MuB);
    unsigned short* MeB  = (unsigned short*)(ws + o_MeB);
    unsigned short* MoB  = (unsigned short*)(ws + o_MoB);
    unsigned short* w1T  = (unsigned short*)(ws + o_w1T);
    unsigned short* vT   = (unsigned short*)(ws + o_vT);
    unsigned short* w2T  = (unsigned short*)(ws + o_w2T);
    unsigned short* pw   = (unsigned short*)(ws + o_pow);
    unsigned short* pwTs = (unsigned short*)(ws + o_powT);
    unsigned short* Q    = (unsigned short*)(ws + o_Q);
    float* y             = (float*)(ws + o_y);
    unsigned short* ybf  = (unsigned short*)(ws + o_ybf);   // reused as obf after qconv
    unsigned short* V    = (unsigned short*)(ws + o_V);
    unsigned short* act  = (unsigned short*)(ws + o_V);     // aliases V (dead after conv)

    // merged prep: rmsnorm + Me/Mo + transposes + buildM + toep
    k_prep<<<dim3(27840), 256, 0, stream>>>(x, rmsw,
                                            (const float4*)Mu, (const float4*)Mp, (const float4*)Mm,
                                            w1, vv, w2, my, phi,
                                            u_b, (S4*)MuB, (S4*)MeB, (S4*)MoB,
                                            w1T, vT, w2T, pw, pwTs, Q, Tt);

    // companion-matrix powers for P=8 taps (p=1..7)
    const int ns[3]   = {1, 2, 4};
    const int cnts[3] = {1, 2, 3};
    for (int s = 0; s < 3; ++s)
        k_pow<<<dim3(4, 2, cnts[s]), 512, 0, stream>>>(pw, pwTs, Q, s, ns[s]);

    k_aru<<<dim3(16, NB), 512, 0, stream>>>(u_b, MuB, y);

    // spectral (folded + parity-split proj): single counted-vmcnt conv pass (4-wave acc[4][8])
    k_proj<<<dim3(16, NB, NKF), 512, 0, stream>>>(u_b, MeB, MoB, sigma, V);
    k_conv<<<dim3(72, NB, KG), 256, 0, stream>>>(V, Tt, y);

    // out = y; ybf = bf16(y)
    k_prep2<<<dim3(NTOT/4/256), 256, 0, stream>>>((const float4*)y, (float4*)out, (S4*)ybf);

    // output AR recurrence (P=8): out += sum_{p=1..7} Q_p y_{t-p}
    k_qconv<<<dim3(16, NB, 7), 512, 0, stream>>>(ybf, Q, out);

    // obf = bf16(out)
    k_cast_out<<<dim3(NTOT/4/256), 256, 0, stream>>>((const float4*)out, (S4*)ybf);

    // MLP + residuals: act = silu(out@w1)*(out@v); out = x + out + act@w2
    k_mlp1f<<<dim3(16, NB, 4), 512, 0, stream>>>(ybf, w1T, vT, act);
    k_mlp2<<<dim3(16, NB, 4), 512, 0, stream>>>(act, w2T, x, out);
}

// Round 16
// 454.441 us; speedup vs baseline: 1.0916x; 1.0916x over previous
//
#include <hip/hip_runtime.h>
#include <hip/hip_bf16.h>
#include <math.h>

#define SLEN 2048
#define DIM 256
#define NB 4
#define NKF 24
#define NH 1024
#define NROW (NB*SLEN)          // 8192
#define NTOT (NB*SLEN*DIM)      // 2097152

#define BM 128
#define BN 256
#define BKK 32
#define PADK 40                 // padded LDS stride for generic (reg-staged) GEMMs

#define KG 3                    // conv k-group blocks
#define KPB 8                   // filters per conv block
#define VELEMS ((size_t)NKF*NB*DIM*SLEN)   // W buffer: 50,331,648 ushorts (100.7 MB)

typedef __attribute__((ext_vector_type(8))) short bf16x8;
typedef __attribute__((ext_vector_type(4))) float f32x4;

struct __align__(16) U4 { unsigned int a, b, c, d; };
struct __align__(8)  S4 { unsigned short x, y, z, w; };

__device__ __forceinline__ unsigned short f2b(float v){
    union { __hip_bfloat16 h; unsigned short u; } cv;
    cv.h = __float2bfloat16(v);
    return cv.u;
}
__device__ __forceinline__ float b2f(unsigned short s){
    union { __hip_bfloat16 h; unsigned short u; } cv;
    cv.u = s;
    return __bfloat162float(cv.h);
}

// async global->LDS, 16B per lane; LDS dest = wave-uniform base + lane*16
__device__ __forceinline__ void gl_lds(const unsigned short* g, unsigned short* l){
    __builtin_amdgcn_global_load_lds((const __attribute__((address_space(1))) void*)g,
                                     (__attribute__((address_space(3))) void*)l, 16, 0, 0);
}

// swizzled slot index within a conv subtile: rows x 4 k-slots of 16B, 2-way-max bank conflicts
__device__ __forceinline__ int swzS(int row, int g){
    return ((row >> 3) << 5) + (g << 3) + ((row & 7) ^ g);
}

// ---------------- merged prep kernel: rmsnorm + casts(Me/Mo) + transposes + buildM + toep ----------------
__global__ void k_prep(const float* __restrict__ x, const float* __restrict__ rmsw,
                       const float4* __restrict__ Mu, const float4* __restrict__ Mp,
                       const float4* __restrict__ Mm,
                       const float* __restrict__ w1, const float* __restrict__ vv,
                       const float* __restrict__ w2, const float* __restrict__ my,
                       const float* __restrict__ phi,
                       unsigned short* __restrict__ u_b,
                       S4* __restrict__ MuB, S4* __restrict__ MeB, S4* __restrict__ MoB,
                       unsigned short* __restrict__ w1T, unsigned short* __restrict__ vT,
                       unsigned short* __restrict__ w2T,
                       unsigned short* __restrict__ pw, unsigned short* __restrict__ pwTs,
                       unsigned short* __restrict__ Q, unsigned short* __restrict__ Tt){
    __shared__ float red[4];
    int bid = blockIdx.x, tix = threadIdx.x;
    if (bid < NROW){
        int row = bid, t = tix;
        float v = x[(size_t)row*DIM + t];
        float ss = v*v;
        #pragma unroll
        for (int o = 32; o > 0; o >>= 1) ss += __shfl_down(ss, o, 64);
        if ((t & 63) == 0) red[t >> 6] = ss;
        __syncthreads();
        float tot = red[0]+red[1]+red[2]+red[3];
        float sc = rsqrtf(tot * (1.0f/256.0f) + 1e-6f);
        u_b[(size_t)row*DIM + t] = f2b(v * sc * rmsw[t]);
        return;
    }
    bid -= NROW;
    if (bid < 192){
        int i = bid*256 + tix;
        float4 v = Mu[i];
        S4 p; p.x=f2b(v.x); p.y=f2b(v.y); p.z=f2b(v.z); p.w=f2b(v.w);
        MuB[i] = p; return;
    }
    bid -= 192;
    if (bid < 1536){
        int i = bid*256 + tix;
        float4 a = Mp[i], b = Mm[i];
        S4 p; p.x=f2b(a.x+b.x); p.y=f2b(a.y+b.y); p.z=f2b(a.z+b.z); p.w=f2b(a.w+b.w);
        MeB[i] = p; return;
    }
    bid -= 1536;
    if (bid < 1536){
        int i = bid*256 + tix;
        float4 a = Mp[i], b = Mm[i];
        S4 p; p.x=f2b(a.x-b.x); p.y=f2b(a.y-b.y); p.z=f2b(a.z-b.z); p.w=f2b(a.w-b.w);
        MoB[i] = p; return;
    }
    bid -= 1536;
    if (bid < 1024){
        int i = bid*256 + tix; int r = i >> 10, c = i & 1023;
        w1T[(size_t)c*DIM + r] = f2b(w1[i]); return;
    }
    bid -= 1024;
    if (bid < 1024){
        int i = bid*256 + tix; int r = i >> 10, c = i & 1023;
        vT[(size_t)c*DIM + r] = f2b(vv[i]); return;
    }
    bid -= 1024;
    if (bid < 1024){
        int i = bid*256 + tix; int r = i >> 8, c = i & 255;
        w2T[(size_t)c*NH + r] = f2b(w2[i]); return;
    }
    bid -= 1024;
    if (bid < 1024){
        int i = bid*256 + tix;
        int r = i >> 9, c = i & 511;
        float v;
        if (r < 256) v = (c < 256) ? my[r*256 + c] : my[256*256 + r*256 + (c - 256)];
        else         v = (c == r - 256) ? 1.0f : 0.0f;
        unsigned short bb = f2b(v);
        pw [262144 + (size_t)r*512 + c] = bb;
        pwTs[(size_t)c*512 + r] = bb;
        if (r < 256 && c < 256) Q[65536 + r*256 + c] = bb;
        return;
    }
    bid -= 1024;
    {
        int i = bid*256 + tix;
        int e   = (i & 7) * 4;
        int row = (i >> 3) & 127;
        int c   = (i >> 10) & 7;
        int rem = (i >> 13) & 15;
        int k   = i >> 17;
        int d0 = rem*128 + row - (c*32 + e);
        S4 p;
        p.x = (d0   >= 0) ? f2b(phi[(size_t)(d0  )*NKF + k]) : (unsigned short)0;
        p.y = (d0-1 >= 0) ? f2b(phi[(size_t)(d0-1)*NKF + k]) : (unsigned short)0;
        p.z = (d0-2 >= 0) ? f2b(phi[(size_t)(d0-2)*NKF + k]) : (unsigned short)0;
        p.w = (d0-3 >= 0) ? f2b(phi[(size_t)(d0-3)*NKF + k]) : (unsigned short)0;
        size_t base = ((size_t)((k*16 + rem)*8 + c)) * 4096;
        *(S4*)&Tt[base + swzS(row, e>>3)*8 + (e&7)] = p;
    }
}

// out = y (f32 copy) and ybf = bf16(y)
__global__ void k_prep2(const float4* __restrict__ y, float4* __restrict__ out, S4* __restrict__ ybf){
    int i = blockIdx.x*256 + threadIdx.x;
    if (i < NTOT/4){
        float4 v = y[i];
        out[i] = v;
        S4 p; p.x=f2b(v.x); p.y=f2b(v.y); p.z=f2b(v.z); p.w=f2b(v.w);
        ybf[i] = p;
    }
}

// obf = bf16(out)
__global__ void k_cast_out(const float4* __restrict__ out, S4* __restrict__ obf){
    int i = blockIdx.x*256 + threadIdx.x;
    if (i < NTOT/4){
        float4 v = out[i];
        S4 p; p.x=f2b(v.x); p.y=f2b(v.y); p.z=f2b(v.z); p.w=f2b(v.w);
        obf[i] = p;
    }
}

// ---------------- shared MFMA tile core (generic reg-staged GEMMs) ----------------

__device__ __forceinline__ void mfma_tile(const unsigned short* Al, const unsigned short* Bl,
                                          f32x4 acc[4][4], int lane, int wr, int wc){
    int cl = lane & 15;
    int kb = (lane >> 4) * 8;
    bf16x8 a[4], b[4];
    #pragma unroll
    for (int mi = 0; mi < 4; ++mi)
        a[mi] = *(const bf16x8*)&Al[(wr*64 + mi*16 + cl)*PADK + kb];
    #pragma unroll
    for (int ni = 0; ni < 4; ++ni)
        b[ni] = *(const bf16x8*)&Bl[(wc*64 + ni*16 + cl)*PADK + kb];
    #pragma unroll
    for (int mi = 0; mi < 4; ++mi)
        #pragma unroll
        for (int ni = 0; ni < 4; ++ni)
            acc[mi][ni] = __builtin_amdgcn_mfma_f32_16x16x32_bf16(a[mi], b[ni], acc[mi][ni], 0, 0, 0);
}

#define GEMM_PROLOG \
    __shared__ unsigned short Al[BM*PADK]; \
    __shared__ unsigned short Bl[BN*PADK]; \
    int tid = threadIdx.x, lane = tid & 63, wv = tid >> 6, wr = wv >> 2, wc = wv & 3; \
    f32x4 acc[4][4]; \
    { f32x4 z = {0.f,0.f,0.f,0.f}; \
      for (int mi=0;mi<4;++mi) for (int ni=0;ni<4;++ni) acc[mi][ni] = z; }

// ---------------- power doubling (P=8 chain): M^(ns+j) = M^j * M^ns ----------------
__global__ __launch_bounds__(512) void k_pow(unsigned short* __restrict__ pw, unsigned short* __restrict__ pwTs,
                                             unsigned short* __restrict__ Q, int s, int ns){
    int mt = blockIdx.x, nt = blockIdx.y;
    int j = 1 + blockIdx.z;
    int p = ns + j;
    int m0 = mt * BM, n0 = nt * BN;
    int fullNeed = (p <= 3) || (j == ns && ns <= 2);
    if (!fullNeed && (m0 >= 256 || n0 >= 256)) return;
    GEMM_PROLOG
    const unsigned short* A = pw   + (size_t)j * 262144;
    const unsigned short* B = pwTs + (size_t)s * 262144;
    for (int k0 = 0; k0 < 512; k0 += BKK){
        __syncthreads();
        { int row = tid >> 2, sg = tid & 3;
          *(U4*)&Al[row*PADK + sg*8] = *(const U4*)&A[(size_t)(m0+row)*512 + k0 + sg*8]; }
        #pragma unroll
        for (int ss = 0; ss < 2; ++ss){ int q = tid + ss*512; int row = q >> 2, sg = q & 3;
          *(U4*)&Bl[row*PADK + sg*8] = *(const U4*)&B[(size_t)(n0+row)*512 + k0 + sg*8]; }
        __syncthreads();
        mfma_tile(Al, Bl, acc, lane, wr, wc);
    }
    int cl = lane & 15, rg = (lane >> 4) * 4;
    #pragma unroll
    for (int mi=0; mi<4; ++mi){
        int rb = m0 + wr*64 + mi*16 + rg;
        #pragma unroll
        for (int ni=0; ni<4; ++ni){
            int col = n0 + wc*64 + ni*16 + cl;
            unsigned short bb[4];
            #pragma unroll
            for (int r=0;r<4;++r) bb[r] = f2b(acc[mi][ni][r]);
            if (p <= 3){
                #pragma unroll
                for (int r=0;r<4;++r) pw[(size_t)p*262144 + (size_t)(rb+r)*512 + col] = bb[r];
            }
            if (j == ns && ns <= 2){
                S4 pk; pk.x=bb[0]; pk.y=bb[1]; pk.z=bb[2]; pk.w=bb[3];
                *(S4*)&pwTs[(size_t)(s+1)*262144 + (size_t)col*512 + rb] = pk;
            }
            if (rb < 256 && col < 256 && p <= 7){
                #pragma unroll
                for (int r=0;r<4;++r) Q[(size_t)p*65536 + (size_t)(rb+r)*256 + col] = bb[r];
            }
        }
    }
}

// ---------------- projection v6 (parity-split) + merged ar_u (z == NKF slice) ----------------
__global__ __launch_bounds__(512) void k_proj(const unsigned short* __restrict__ u,
                                              const unsigned short* __restrict__ Me,
                                              const unsigned short* __restrict__ Mo,
                                              const unsigned short* __restrict__ Mu,
                                              const float* __restrict__ sigma,
                                              unsigned short* __restrict__ V,
                                              float* __restrict__ y){
    __shared__ unsigned short Al[BM*PADK];
    __shared__ unsigned short Bl0[BN*PADK];
    __shared__ unsigned short Bl1[BN*PADK];
    int tid = threadIdx.x, lane = tid & 63, wv = tid >> 6, wr = wv >> 2, wc = wv & 3;
    f32x4 acc[4][4];
    { f32x4 z = {0.f,0.f,0.f,0.f};
      for (int mi=0;mi<4;++mi) for (int ni=0;ni<4;++ni) acc[mi][ni] = z; }
    int tt = blockIdx.x, b = blockIdx.y, k = blockIdx.z;
    int t0 = tt * BM;
    int cl = lane & 15, rg = (lane >> 4) * 4;

    if (k == NKF){
        // ---- ar_u slice: y = sum_i shift(u,i) @ Mu[i]^T ----
        const unsigned short* Ab = u + (size_t)b*SLEN*DIM;
        for (int i = 0; i < 3; ++i){
            const unsigned short* Bsrc = Mu + (size_t)i*65536;
            for (int k0 = 0; k0 < 256; k0 += BKK){
                __syncthreads();
                { int row = tid >> 2, sg = tid & 3; int t = t0 + row - i;
                  U4 val; val.a=val.b=val.c=val.d=0u;
                  if (t >= 0) val = *(const U4*)&Ab[(size_t)t*DIM + k0 + sg*8];
                  *(U4*)&Al[row*PADK + sg*8] = val; }
                #pragma unroll
                for (int s = 0; s < 2; ++s){ int q = tid + s*512; int row = q >> 2, sg = q & 3;
                  *(U4*)&Bl0[row*PADK + sg*8] = *(const U4*)&Bsrc[(size_t)row*DIM + k0 + sg*8]; }
                __syncthreads();
                mfma_tile(Al, Bl0, acc, lane, wr, wc);
            }
        }
        #pragma unroll
        for (int mi=0; mi<4; ++mi){
            int tb = t0 + wr*64 + mi*16 + rg;
            #pragma unroll
            for (int ni=0; ni<4; ++ni){
                int o = wc*64 + ni*16 + cl;
                #pragma unroll
                for (int r=0;r<4;++r) y[((size_t)b*SLEN + tb + r)*DIM + o] = acc[mi][ni][r];
            }
        }
        return;
    }

    // ---- spectral projection slice ----
    float sr = powf(sigma[k], 0.25f);
    const unsigned short* Asrc  = u + ((size_t)b*SLEN)*DIM;
    const unsigned short* B0src = Me + (size_t)k*65536;
    const unsigned short* B1src = Mo + (size_t)k*65536;
    for (int k0 = 0; k0 < 256; k0 += BKK){
        __syncthreads();
        { int row = tid >> 2, sg = tid & 3;
          int t = (row < 64) ? (t0 + 2*row) : (t0 + 2*(row-64) + 1);
          *(U4*)&Al[row*PADK + sg*8] = *(const U4*)&Asrc[(size_t)t*DIM + k0 + sg*8]; }
        #pragma unroll
        for (int s = 0; s < 2; ++s){ int q = tid + s*512; int row = q >> 2, sg = q & 3;
          *(U4*)&Bl0[row*PADK + sg*8] = *(const U4*)&B0src[(size_t)row*DIM + k0 + sg*8];
          *(U4*)&Bl1[row*PADK + sg*8] = *(const U4*)&B1src[(size_t)row*DIM + k0 + sg*8]; }
        __syncthreads();
        mfma_tile(Al, wr ? Bl1 : Bl0, acc, lane, wr, wc);
    }
    const int TRS = 136;
    #pragma unroll
    for (int h = 0; h < 2; ++h){
        __syncthreads();
        if ((wc >> 1) == h){
            unsigned short* Trm = (wc & 1) ? Bl1 : Bl0;
            #pragma unroll
            for (int mi=0; mi<4; ++mi){
                #pragma unroll
                for (int ni=0; ni<4; ++ni){
                    int ol = ni*16 + cl;
                    S4 pk;
                    pk.x = f2b(sr*acc[mi][ni][0]); pk.y = f2b(sr*acc[mi][ni][1]);
                    pk.z = f2b(sr*acc[mi][ni][2]); pk.w = f2b(sr*acc[mi][ni][3]);
                    #pragma unroll
                    for (int r=0; r<4; ++r){
                        int lr = mi*16 + rg + r;
                        int dt = wr ? (2*lr + 1) : (2*lr);
                        Trm[ol*TRS + dt] = (&pk.x)[r];
                    }
                }
            }
        }
        __syncthreads();
        { int row = tid >> 3, seg = tid & 7;
          int tb = (t0 >> 5) + (seg >> 1);
          int g0 = (seg & 1) * 2;
          size_t sb = ((size_t)(k*NB + b)*64 + tb) * 8192;
          #pragma unroll
          for (int q = 0; q < 2; ++q){
              const unsigned short* Trm = q ? Bl1 : Bl0;
              U4 v0 = *(const U4*)&Trm[row*TRS + seg*16];
              U4 v1 = *(const U4*)&Trm[row*TRS + seg*16 + 8];
              int o  = (2*h + q)*64 + row;
              *(U4*)&V[sb + swzS(o, g0  )*8] = v0;
              *(U4*)&V[sb + swzS(o, g0+1)*8] = v1;
          }
        }
    }
}

// ---------------- causal Toeplitz conv v9 (reverted, proven): 8 waves, 3-buffer depth-2 vmcnt(3) ----------------
__global__ __launch_bounds__(512) void k_conv(const unsigned short* __restrict__ V,
                                              const unsigned short* __restrict__ Tt,
                                              float* __restrict__ y){
    __shared__ __align__(16) unsigned short Abuf[3][4096];
    __shared__ __align__(16) unsigned short Bbuf[3][8192];
    int tid = threadIdx.x, lane = tid & 63, wv = tid >> 6, wr = wv >> 2, wc = wv & 3;
    f32x4 acc[4][4];
    { f32x4 z = {0.f,0.f,0.f,0.f};
      for (int mi=0;mi<4;++mi) for (int ni=0;ni<4;++ni) acc[mi][ni] = z; }

    int b = blockIdx.y, kg = blockIdx.z;
    int px0 = blockIdx.x;
    int px = (px0 & 7)*9 + (px0 >> 3);
    int jx = 0, rem = px;
    #pragma unroll
    for (int j = 0; j < 8; ++j){
        int c = 16 - 2*j;
        if (rem < c){ jx = j; break; }
        rem -= c;
    }
    int tt = 2*jx + rem;
    int t0 = tt*BM;
    int cl = lane & 15, g = lane >> 4;

    int aoff[4], boff[4];
    #pragma unroll
    for (int mi = 0; mi < 4; ++mi) aoff[mi] = swzS(wr*64 + mi*16 + cl, g) << 4;
    #pragma unroll
    for (int ni = 0; ni < 4; ++ni) boff[ni] = swzS(wc*64 + ni*16 + cl, g) << 4;

    const unsigned short* Abase = Tt + (size_t)((kg*KPB*16 + rem)*8) * 4096;
    const unsigned short* Bbase = V  + (((size_t)(kg*KPB*NB + b)*64 + jx*8)) * 8192;

    auto stage = [&](int bi, int step){
        int kk = step >> 3, ts = step & 7;
        const unsigned short* As = Abase + ((size_t)kk*16*8 + ts)*4096 + wv*512;
        const unsigned short* Bs = Bbase + ((size_t)kk*NB*64 + ts)*8192 + wv*1024;
        gl_lds(As + lane*8,       &Abuf[bi][wv*512]);
        gl_lds(Bs + lane*8,       &Bbuf[bi][wv*1024]);
        gl_lds(Bs + 512 + lane*8, &Bbuf[bi][wv*1024 + 512]);
    };

    auto compute = [&](int bi){
        bf16x8 a[4], bb[4];
        #pragma unroll
        for (int mi = 0; mi < 4; ++mi)
            a[mi] = *(const bf16x8*)((const char*)Abuf[bi] + aoff[mi]);
        #pragma unroll
        for (int ni = 0; ni < 4; ++ni)
            bb[ni] = *(const bf16x8*)((const char*)Bbuf[bi] + boff[ni]);
        #pragma unroll
        for (int mi = 0; mi < 4; ++mi)
            #pragma unroll
            for (int ni = 0; ni < 4; ++ni)
                acc[mi][ni] = __builtin_amdgcn_mfma_f32_16x16x32_bf16(a[mi], bb[ni], acc[mi][ni], 0, 0, 0);
    };

    stage(0, 0);
    stage(1, 1);
    int cur = 0;
    for (int t = 0; t < KPB*8 - 1; ++t){
        asm volatile("s_waitcnt vmcnt(3)" ::: "memory");
        __builtin_amdgcn_s_barrier();
        __builtin_amdgcn_sched_barrier(0);
        compute(cur);
        if (t + 2 < KPB*8){
            int nb = cur + 2; if (nb >= 3) nb -= 3;
            stage(nb, t + 2);
        }
        cur = (cur == 2) ? 0 : cur + 1;
    }
    asm volatile("s_waitcnt vmcnt(0)" ::: "memory");
    __builtin_amdgcn_s_barrier();
    __builtin_amdgcn_sched_barrier(0);
    compute(cur);

    int rg = (lane >> 4) * 4;
    #pragma unroll
    for (int mi=0; mi<4; ++mi){
        int tb = t0 + wr*64 + mi*16 + rg;
        #pragma unroll
        for (int ni=0; ni<4; ++ni){
            int o = wc*64 + ni*16 + cl;
            #pragma unroll
            for (int r=0;r<4;++r) atomicAdd(&y[((size_t)b*SLEN + tb + r)*DIM + o], acc[mi][ni][r]);
        }
    }
}

// ---------------- output AR via truncated Q-filter (P=8): gz=7, one tap per block ----------------
__global__ __launch_bounds__(512) void k_qconv(const unsigned short* __restrict__ ybf,
                                               const unsigned short* __restrict__ Q,
                                               float* __restrict__ yh){
    GEMM_PROLOG
    int tt = blockIdx.x, b = blockIdx.y, gz = blockIdx.z;
    int t0 = tt * BM;
    const unsigned short* ysrc = ybf + (size_t)b*SLEN*DIM;
    int p = gz + 1;                        // 1..7
    const unsigned short* Qp = Q + (size_t)p*65536;
    for (int k0 = 0; k0 < 256; k0 += BKK){
        __syncthreads();
        { int row = tid >> 2, sg = tid & 3; int t = t0 + row - p;
          U4 val; val.a=val.b=val.c=val.d=0u;
          if (t >= 0) val = *(const U4*)&ysrc[(size_t)t*DIM + k0 + sg*8];
          *(U4*)&Al[row*PADK + sg*8] = val; }
        #pragma unroll
        for (int s = 0; s < 2; ++s){ int q = tid + s*512; int row = q >> 2, sg = q & 3;
          *(U4*)&Bl[row*PADK + sg*8] = *(const U4*)&Qp[(size_t)row*256 + k0 + sg*8]; }
        __syncthreads();
        mfma_tile(Al, Bl, acc, lane, wr, wc);
    }
    int cl = lane & 15, rg = (lane >> 4) * 4;
    #pragma unroll
    for (int mi=0; mi<4; ++mi){
        int tb = t0 + wr*64 + mi*16 + rg;
        #pragma unroll
        for (int ni=0; ni<4; ++ni){
            int o = wc*64 + ni*16 + cl;
            #pragma unroll
            for (int r=0;r<4;++r) atomicAdd(&yh[((size_t)b*SLEN + tb + r)*DIM + o], acc[mi][ni][r]);
        }
    }
}

// ---------------- fused MLP GEMM1 (bf16 A): act = silu(.@w1)*(.@v) ----------------
__global__ __launch_bounds__(512) void k_mlp1f(const unsigned short* __restrict__ obf,
                                               const unsigned short* __restrict__ w1T,
                                               const unsigned short* __restrict__ vT,
                                               unsigned short* __restrict__ act){
    __shared__ unsigned short Al[BM*PADK];
    __shared__ unsigned short Bl0[BN*PADK];
    __shared__ unsigned short Bl1[BN*PADK];
    int tid = threadIdx.x, lane = tid & 63, wv = tid >> 6, wr = wv >> 2, wc = wv & 3;
    f32x4 acc0[4][4], acc1[4][4];
    { f32x4 z = {0.f,0.f,0.f,0.f};
      for (int mi=0;mi<4;++mi) for (int ni=0;ni<4;++ni){ acc0[mi][ni] = z; acc1[mi][ni] = z; } }
    int tt = blockIdx.x, b = blockIdx.y, nt = blockIdx.z;
    int t0 = tt * BM, h0 = nt * 256;
    const unsigned short* Asrc = obf + ((size_t)b*SLEN + t0)*DIM;
    const unsigned short* B0src = w1T + (size_t)h0*DIM;
    const unsigned short* B1src = vT  + (size_t)h0*DIM;
    for (int k0 = 0; k0 < 256; k0 += BKK){
        __syncthreads();
        { int row = tid >> 2, sg = tid & 3;
          *(U4*)&Al[row*PADK + sg*8] = *(const U4*)&Asrc[(size_t)row*DIM + k0 + sg*8]; }
        #pragma unroll
        for (int s = 0; s < 2; ++s){ int q = tid + s*512; int row = q >> 2, sg = q & 3;
          *(U4*)&Bl0[row*PADK + sg*8] = *(const U4*)&B0src[(size_t)row*DIM + k0 + sg*8];
          *(U4*)&Bl1[row*PADK + sg*8] = *(const U4*)&B1src[(size_t)row*DIM + k0 + sg*8]; }
        __syncthreads();
        mfma_tile(Al, Bl0, acc0, lane, wr, wc);
        mfma_tile(Al, Bl1, acc1, lane, wr, wc);
    }
    int cl = lane & 15, rg = (lane >> 4) * 4;
    #pragma unroll
    for (int mi=0; mi<4; ++mi){
        int tb = t0 + wr*64 + mi*16 + rg;
        #pragma unroll
        for (int ni=0; ni<4; ++ni){
            int h = h0 + wc*64 + ni*16 + cl;
            #pragma unroll
            for (int r=0; r<4; ++r){
                float av = acc0[mi][ni][r];
                float sv = av / (1.0f + expf(-av));
                act[(size_t)(b*SLEN + tb + r)*NH + h] = f2b(sv * acc1[mi][ni][r]);
            }
        }
    }
}

// ---------------- MLP GEMM2 (K split z=4): out(=yhat) += act@w2 partial + (z==0)*x ----------------
__global__ __launch_bounds__(512) void k_mlp2(const unsigned short* __restrict__ act,
                                              const unsigned short* __restrict__ w2T,
                                              const float* __restrict__ x,
                                              float* __restrict__ out){
    GEMM_PROLOG
    int tt = blockIdx.x, b = blockIdx.y, ks = blockIdx.z;
    int t0 = tt * BM;
    size_t bt0 = (size_t)b*SLEN + t0;
    for (int k0 = ks*256; k0 < ks*256 + 256; k0 += BKK){
        __syncthreads();
        { int row = tid >> 2, sg = tid & 3;
          *(U4*)&Al[row*PADK + sg*8] = *(const U4*)&act[(bt0 + row)*NH + k0 + sg*8]; }
        #pragma unroll
        for (int s = 0; s < 2; ++s){ int q = tid + s*512; int row = q >> 2, sg = q & 3;
          *(U4*)&Bl[row*PADK + sg*8] = *(const U4*)&w2T[(size_t)row*NH + k0 + sg*8]; }
        __syncthreads();
        mfma_tile(Al, Bl, acc, lane, wr, wc);
    }
    int cl = lane & 15, rg = (lane >> 4) * 4;
    #pragma unroll
    for (int mi=0; mi<4; ++mi){
        #pragma unroll
        for (int ni=0; ni<4; ++ni){
            int o = wc*64 + ni*16 + cl;
            #pragma unroll
            for (int r=0;r<4;++r){
                size_t idx = (bt0 + wr*64 + mi*16 + rg + r)*DIM + o;
                float add = acc[mi][ni][r] + (ks == 0 ? x[idx] : 0.0f);
                atomicAdd(&out[idx], add);
            }
        }
    }
}

// ---------------- host ----------------

extern "C" void kernel_launch(void* const* d_in, const int* in_sizes, int n_in,
                              void* d_out, int out_size, void* d_ws, size_t ws_size,
                              hipStream_t stream) {
    (void)in_sizes; (void)n_in; (void)out_size;
    const float* x     = (const float*)d_in[0];
    const float* sigma = (const float*)d_in[1];
    const float* phi   = (const float*)d_in[2];
    const float* rmsw  = (const float*)d_in[3];
    const float* Mu    = (const float*)d_in[4];
    const float* Mp    = (const float*)d_in[5];
    const float* Mm    = (const float*)d_in[6];
    const float* my    = (const float*)d_in[7];
    const float* w1    = (const float*)d_in[8];
    const float* vv    = (const float*)d_in[9];
    const float* w2    = (const float*)d_in[10];
    float* out = (float*)d_out;

    char* ws = (char*)d_ws;
    size_t off = 0;
    auto alloc = [&](size_t bytes){ size_t o = off; off += (bytes + 255) & ~(size_t)255; return o; };

    size_t o_u    = alloc((size_t)NROW*DIM*2);
    size_t o_T    = alloc((size_t)NKF*16*128*256*2);
    size_t o_MuB  = alloc((size_t)3*65536*2);
    size_t o_MeB  = alloc((size_t)NKF*65536*2);
    size_t o_MoB  = alloc((size_t)NKF*65536*2);
    size_t o_w1T  = alloc((size_t)NH*DIM*2);
    size_t o_vT   = alloc((size_t)NH*DIM*2);
    size_t o_w2T  = alloc((size_t)DIM*NH*2);
    size_t o_pow  = alloc((size_t)5*262144*2);
    size_t o_powT = alloc((size_t)3*262144*2);
    size_t o_Q    = alloc((size_t)8*65536*2);
    size_t o_y    = alloc((size_t)NTOT*4);
    size_t o_ybf  = alloc((size_t)NTOT*2);
    size_t o_V    = alloc(VELEMS*2);
    if (off > ws_size) return;

    unsigned short* u_b  = (unsigned short*)(ws + o_u);
    unsigned short* Tt   = (unsigned short*)(ws + o_T);
    unsigned short* MuB  = (unsigned short*)(ws + o_MuB);
    unsigned short* MeB  = (unsigned short*)(ws + o_MeB);
    unsigned short* MoB  = (unsigned short*)(ws + o_MoB);
    unsigned short* w1T  = (unsigned short*)(ws + o_w1T);
    unsigned short* vT   = (unsigned short*)(ws + o_vT);
    unsigned short* w2T  = (unsigned short*)(ws + o_w2T);
    unsigned short* pw   = (unsigned short*)(ws + o_pow);
    unsigned short* pwTs = (unsigned short*)(ws + o_powT);
    unsigned short* Q    = (unsigned short*)(ws + o_Q);
    float* y             = (float*)(ws + o_y);
    unsigned short* ybf  = (unsigned short*)(ws + o_ybf);   // reused as obf after qconv
    unsigned short* V    = (unsigned short*)(ws + o_V);
    unsigned short* act  = (unsigned short*)(ws + o_V);     // aliases V (dead after conv)

    // merged prep: rmsnorm + Me/Mo + transposes + buildM + toep
    k_prep<<<dim3(27840), 256, 0, stream>>>(x, rmsw,
                                            (const float4*)Mu, (const float4*)Mp, (const float4*)Mm,
                                            w1, vv, w2, my, phi,
                                            u_b, (S4*)MuB, (S4*)MeB, (S4*)MoB,
                                            w1T, vT, w2T, pw, pwTs, Q, Tt);

    // companion-matrix powers for P=8 taps (p=1..7)
    const int ns[3]   = {1, 2, 4};
    const int cnts[3] = {1, 2, 3};
    for (int s = 0; s < 3; ++s)
        k_pow<<<dim3(4, 2, cnts[s]), 512, 0, stream>>>(pw, pwTs, Q, s, ns[s]);

    // spectral projection (parity-split) + merged ar_u (z == NKF)
    k_proj<<<dim3(16, NB, NKF + 1), 512, 0, stream>>>(u_b, MeB, MoB, MuB, sigma, V, y);

    // single counted-vmcnt conv pass (8-wave v9, proven)
    k_conv<<<dim3(72, NB, KG), 512, 0, stream>>>(V, Tt, y);

    // out = y; ybf = bf16(y)
    k_prep2<<<dim3(NTOT/4/256), 256, 0, stream>>>((const float4*)y, (float4*)out, (S4*)ybf);

    // output AR recurrence (P=8): out += sum_{p=1..7} Q_p y_{t-p}
    k_qconv<<<dim3(16, NB, 7), 512, 0, stream>>>(ybf, Q, out);

    // obf = bf16(out)
    k_cast_out<<<dim3(NTOT/4/256), 256, 0, stream>>>((const float4*)out, (S4*)ybf);

    // MLP + residuals: act = silu(out@w1)*(out@v); out = x + out + act@w2
    k_mlp1f<<<dim3(16, NB, 4), 512, 0, stream>>>(ybf, w1T, vT, act);
    k_mlp2<<<dim3(16, NB, 4), 512, 0, stream>>>(act, w2T, x, out);
}

// Round 17
// 449.776 us; speedup vs baseline: 1.1029x; 1.0104x over previous
//
#include <hip/hip_runtime.h>
#include <hip/hip_bf16.h>
#include <math.h>

#define SLEN 2048
#define DIM 256
#define NB 4
#define NKF 24
#define NH 1024
#define NROW (NB*SLEN)          // 8192
#define NTOT (NB*SLEN*DIM)      // 2097152

#define BM 128
#define BN 256
#define BKK 32
#define PADK 40                 // padded LDS stride for generic (reg-staged) GEMMs

#define KG 3                    // conv k-group blocks
#define KPB 8                   // filters per conv block
#define VELEMS ((size_t)NKF*NB*DIM*SLEN)   // W buffer: 50,331,648 ushorts (100.7 MB)

typedef __attribute__((ext_vector_type(8))) short bf16x8;
typedef __attribute__((ext_vector_type(4))) float f32x4;

struct __align__(16) U4 { unsigned int a, b, c, d; };
struct __align__(8)  S4 { unsigned short x, y, z, w; };

__device__ __forceinline__ unsigned short f2b(float v){
    union { __hip_bfloat16 h; unsigned short u; } cv;
    cv.h = __float2bfloat16(v);
    return cv.u;
}
__device__ __forceinline__ float b2f(unsigned short s){
    union { __hip_bfloat16 h; unsigned short u; } cv;
    cv.u = s;
    return __bfloat162float(cv.h);
}

// async global->LDS, 16B per lane; LDS dest = wave-uniform base + lane*16
__device__ __forceinline__ void gl_lds(const unsigned short* g, unsigned short* l){
    __builtin_amdgcn_global_load_lds((const __attribute__((address_space(1))) void*)g,
                                     (__attribute__((address_space(3))) void*)l, 16, 0, 0);
}

// swizzled slot index within a conv subtile: rows x 4 k-slots of 16B, 2-way-max bank conflicts
__device__ __forceinline__ int swzS(int row, int g){
    return ((row >> 3) << 5) + (g << 3) + ((row & 7) ^ g);
}

// ---------------- merged prep kernel: rmsnorm + casts(Me/Mo) + transposes + buildM + toep ----------------
__global__ void k_prep(const float* __restrict__ x, const float* __restrict__ rmsw,
                       const float4* __restrict__ Mu, const float4* __restrict__ Mp,
                       const float4* __restrict__ Mm,
                       const float* __restrict__ w1, const float* __restrict__ vv,
                       const float* __restrict__ w2, const float* __restrict__ my,
                       const float* __restrict__ phi,
                       unsigned short* __restrict__ u_b,
                       S4* __restrict__ MuB, S4* __restrict__ MeB, S4* __restrict__ MoB,
                       unsigned short* __restrict__ w1T, unsigned short* __restrict__ vT,
                       unsigned short* __restrict__ w2T,
                       unsigned short* __restrict__ pw, unsigned short* __restrict__ pwTs,
                       unsigned short* __restrict__ Q, unsigned short* __restrict__ Tt){
    __shared__ float red[4];
    int bid = blockIdx.x, tix = threadIdx.x;
    if (bid < NROW){
        int row = bid, t = tix;
        float v = x[(size_t)row*DIM + t];
        float ss = v*v;
        #pragma unroll
        for (int o = 32; o > 0; o >>= 1) ss += __shfl_down(ss, o, 64);
        if ((t & 63) == 0) red[t >> 6] = ss;
        __syncthreads();
        float tot = red[0]+red[1]+red[2]+red[3];
        float sc = rsqrtf(tot * (1.0f/256.0f) + 1e-6f);
        u_b[(size_t)row*DIM + t] = f2b(v * sc * rmsw[t]);
        return;
    }
    bid -= NROW;
    if (bid < 192){
        int i = bid*256 + tix;
        float4 v = Mu[i];
        S4 p; p.x=f2b(v.x); p.y=f2b(v.y); p.z=f2b(v.z); p.w=f2b(v.w);
        MuB[i] = p; return;
    }
    bid -= 192;
    if (bid < 1536){
        int i = bid*256 + tix;
        float4 a = Mp[i], b = Mm[i];
        S4 p; p.x=f2b(a.x+b.x); p.y=f2b(a.y+b.y); p.z=f2b(a.z+b.z); p.w=f2b(a.w+b.w);
        MeB[i] = p; return;
    }
    bid -= 1536;
    if (bid < 1536){
        int i = bid*256 + tix;
        float4 a = Mp[i], b = Mm[i];
        S4 p; p.x=f2b(a.x-b.x); p.y=f2b(a.y-b.y); p.z=f2b(a.z-b.z); p.w=f2b(a.w-b.w);
        MoB[i] = p; return;
    }
    bid -= 1536;
    if (bid < 1024){
        int i = bid*256 + tix; int r = i >> 10, c = i & 1023;
        w1T[(size_t)c*DIM + r] = f2b(w1[i]); return;
    }
    bid -= 1024;
    if (bid < 1024){
        int i = bid*256 + tix; int r = i >> 10, c = i & 1023;
        vT[(size_t)c*DIM + r] = f2b(vv[i]); return;
    }
    bid -= 1024;
    if (bid < 1024){
        int i = bid*256 + tix; int r = i >> 8, c = i & 255;
        w2T[(size_t)c*NH + r] = f2b(w2[i]); return;
    }
    bid -= 1024;
    if (bid < 1024){
        int i = bid*256 + tix;
        int r = i >> 9, c = i & 511;
        float v;
        if (r < 256) v = (c < 256) ? my[r*256 + c] : my[256*256 + r*256 + (c - 256)];
        else         v = (c == r - 256) ? 1.0f : 0.0f;
        unsigned short bb = f2b(v);
        pw [262144 + (size_t)r*512 + c] = bb;
        pwTs[(size_t)c*512 + r] = bb;
        if (r < 256 && c < 256) Q[65536 + r*256 + c] = bb;
        return;
    }
    bid -= 1024;
    {
        int i = bid*256 + tix;
        int e   = (i & 7) * 4;
        int row = (i >> 3) & 127;
        int c   = (i >> 10) & 7;
        int rem = (i >> 13) & 15;
        int k   = i >> 17;
        int d0 = rem*128 + row - (c*32 + e);
        S4 p;
        p.x = (d0   >= 0) ? f2b(phi[(size_t)(d0  )*NKF + k]) : (unsigned short)0;
        p.y = (d0-1 >= 0) ? f2b(phi[(size_t)(d0-1)*NKF + k]) : (unsigned short)0;
        p.z = (d0-2 >= 0) ? f2b(phi[(size_t)(d0-2)*NKF + k]) : (unsigned short)0;
        p.w = (d0-3 >= 0) ? f2b(phi[(size_t)(d0-3)*NKF + k]) : (unsigned short)0;
        size_t base = ((size_t)((k*16 + rem)*8 + c)) * 4096;
        *(S4*)&Tt[base + swzS(row, e>>3)*8 + (e&7)] = p;
    }
}

// out = y (f32 copy) and ybf = bf16(y)
__global__ void k_prep2(const float4* __restrict__ y, float4* __restrict__ out, S4* __restrict__ ybf){
    int i = blockIdx.x*256 + threadIdx.x;
    if (i < NTOT/4){
        float4 v = y[i];
        out[i] = v;
        S4 p; p.x=f2b(v.x); p.y=f2b(v.y); p.z=f2b(v.z); p.w=f2b(v.w);
        ybf[i] = p;
    }
}

// ---------------- shared MFMA tile core (generic reg-staged GEMMs) ----------------

__device__ __forceinline__ void mfma_tile(const unsigned short* Al, const unsigned short* Bl,
                                          f32x4 acc[4][4], int lane, int wr, int wc){
    int cl = lane & 15;
    int kb = (lane >> 4) * 8;
    bf16x8 a[4], b[4];
    #pragma unroll
    for (int mi = 0; mi < 4; ++mi)
        a[mi] = *(const bf16x8*)&Al[(wr*64 + mi*16 + cl)*PADK + kb];
    #pragma unroll
    for (int ni = 0; ni < 4; ++ni)
        b[ni] = *(const bf16x8*)&Bl[(wc*64 + ni*16 + cl)*PADK + kb];
    #pragma unroll
    for (int mi = 0; mi < 4; ++mi)
        #pragma unroll
        for (int ni = 0; ni < 4; ++ni)
            acc[mi][ni] = __builtin_amdgcn_mfma_f32_16x16x32_bf16(a[mi], b[ni], acc[mi][ni], 0, 0, 0);
}

#define GEMM_PROLOG \
    __shared__ unsigned short Al[BM*PADK]; \
    __shared__ unsigned short Bl[BN*PADK]; \
    int tid = threadIdx.x, lane = tid & 63, wv = tid >> 6, wr = wv >> 2, wc = wv & 3; \
    f32x4 acc[4][4]; \
    { f32x4 z = {0.f,0.f,0.f,0.f}; \
      for (int mi=0;mi<4;++mi) for (int ni=0;ni<4;++ni) acc[mi][ni] = z; }

// ---------------- power doubling (P=8 chain): M^(ns+j) = M^j * M^ns ----------------
__global__ __launch_bounds__(512) void k_pow(unsigned short* __restrict__ pw, unsigned short* __restrict__ pwTs,
                                             unsigned short* __restrict__ Q, int s, int ns){
    int mt = blockIdx.x, nt = blockIdx.y;
    int j = 1 + blockIdx.z;
    int p = ns + j;
    int m0 = mt * BM, n0 = nt * BN;
    int fullNeed = (p <= 3) || (j == ns && ns <= 2);
    if (!fullNeed && (m0 >= 256 || n0 >= 256)) return;
    GEMM_PROLOG
    const unsigned short* A = pw   + (size_t)j * 262144;
    const unsigned short* B = pwTs + (size_t)s * 262144;
    for (int k0 = 0; k0 < 512; k0 += BKK){
        __syncthreads();
        { int row = tid >> 2, sg = tid & 3;
          *(U4*)&Al[row*PADK + sg*8] = *(const U4*)&A[(size_t)(m0+row)*512 + k0 + sg*8]; }
        #pragma unroll
        for (int ss = 0; ss < 2; ++ss){ int q = tid + ss*512; int row = q >> 2, sg = q & 3;
          *(U4*)&Bl[row*PADK + sg*8] = *(const U4*)&B[(size_t)(n0+row)*512 + k0 + sg*8]; }
        __syncthreads();
        mfma_tile(Al, Bl, acc, lane, wr, wc);
    }
    int cl = lane & 15, rg = (lane >> 4) * 4;
    #pragma unroll
    for (int mi=0; mi<4; ++mi){
        int rb = m0 + wr*64 + mi*16 + rg;
        #pragma unroll
        for (int ni=0; ni<4; ++ni){
            int col = n0 + wc*64 + ni*16 + cl;
            unsigned short bb[4];
            #pragma unroll
            for (int r=0;r<4;++r) bb[r] = f2b(acc[mi][ni][r]);
            if (p <= 3){
                #pragma unroll
                for (int r=0;r<4;++r) pw[(size_t)p*262144 + (size_t)(rb+r)*512 + col] = bb[r];
            }
            if (j == ns && ns <= 2){
                S4 pk; pk.x=bb[0]; pk.y=bb[1]; pk.z=bb[2]; pk.w=bb[3];
                *(S4*)&pwTs[(size_t)(s+1)*262144 + (size_t)col*512 + rb] = pk;
            }
            if (rb < 256 && col < 256 && p <= 7){
                #pragma unroll
                for (int r=0;r<4;++r) Q[(size_t)p*65536 + (size_t)(rb+r)*256 + col] = bb[r];
            }
        }
    }
}

// ---------------- projection v6 (parity-split) + merged ar_u (z == NKF slice) ----------------
__global__ __launch_bounds__(512) void k_proj(const unsigned short* __restrict__ u,
                                              const unsigned short* __restrict__ Me,
                                              const unsigned short* __restrict__ Mo,
                                              const unsigned short* __restrict__ Mu,
                                              const float* __restrict__ sigma,
                                              unsigned short* __restrict__ V,
                                              float* __restrict__ y){
    __shared__ unsigned short Al[BM*PADK];
    __shared__ unsigned short Bl0[BN*PADK];
    __shared__ unsigned short Bl1[BN*PADK];
    int tid = threadIdx.x, lane = tid & 63, wv = tid >> 6, wr = wv >> 2, wc = wv & 3;
    f32x4 acc[4][4];
    { f32x4 z = {0.f,0.f,0.f,0.f};
      for (int mi=0;mi<4;++mi) for (int ni=0;ni<4;++ni) acc[mi][ni] = z; }
    int tt = blockIdx.x, b = blockIdx.y, k = blockIdx.z;
    int t0 = tt * BM;
    int cl = lane & 15, rg = (lane >> 4) * 4;

    if (k == NKF){
        const unsigned short* Ab = u + (size_t)b*SLEN*DIM;
        for (int i = 0; i < 3; ++i){
            const unsigned short* Bsrc = Mu + (size_t)i*65536;
            for (int k0 = 0; k0 < 256; k0 += BKK){
                __syncthreads();
                { int row = tid >> 2, sg = tid & 3; int t = t0 + row - i;
                  U4 val; val.a=val.b=val.c=val.d=0u;
                  if (t >= 0) val = *(const U4*)&Ab[(size_t)t*DIM + k0 + sg*8];
                  *(U4*)&Al[row*PADK + sg*8] = val; }
                #pragma unroll
                for (int s = 0; s < 2; ++s){ int q = tid + s*512; int row = q >> 2, sg = q & 3;
                  *(U4*)&Bl0[row*PADK + sg*8] = *(const U4*)&Bsrc[(size_t)row*DIM + k0 + sg*8]; }
                __syncthreads();
                mfma_tile(Al, Bl0, acc, lane, wr, wc);
            }
        }
        #pragma unroll
        for (int mi=0; mi<4; ++mi){
            int tb = t0 + wr*64 + mi*16 + rg;
            #pragma unroll
            for (int ni=0; ni<4; ++ni){
                int o = wc*64 + ni*16 + cl;
                #pragma unroll
                for (int r=0;r<4;++r) y[((size_t)b*SLEN + tb + r)*DIM + o] = acc[mi][ni][r];
            }
        }
        return;
    }

    float sr = powf(sigma[k], 0.25f);
    const unsigned short* Asrc  = u + ((size_t)b*SLEN)*DIM;
    const unsigned short* B0src = Me + (size_t)k*65536;
    const unsigned short* B1src = Mo + (size_t)k*65536;
    for (int k0 = 0; k0 < 256; k0 += BKK){
        __syncthreads();
        { int row = tid >> 2, sg = tid & 3;
          int t = (row < 64) ? (t0 + 2*row) : (t0 + 2*(row-64) + 1);
          *(U4*)&Al[row*PADK + sg*8] = *(const U4*)&Asrc[(size_t)t*DIM + k0 + sg*8]; }
        #pragma unroll
        for (int s = 0; s < 2; ++s){ int q = tid + s*512; int row = q >> 2, sg = q & 3;
          *(U4*)&Bl0[row*PADK + sg*8] = *(const U4*)&B0src[(size_t)row*DIM + k0 + sg*8];
          *(U4*)&Bl1[row*PADK + sg*8] = *(const U4*)&B1src[(size_t)row*DIM + k0 + sg*8]; }
        __syncthreads();
        mfma_tile(Al, wr ? Bl1 : Bl0, acc, lane, wr, wc);
    }
    const int TRS = 136;
    #pragma unroll
    for (int h = 0; h < 2; ++h){
        __syncthreads();
        if ((wc >> 1) == h){
            unsigned short* Trm = (wc & 1) ? Bl1 : Bl0;
            #pragma unroll
            for (int mi=0; mi<4; ++mi){
                #pragma unroll
                for (int ni=0; ni<4; ++ni){
                    int ol = ni*16 + cl;
                    S4 pk;
                    pk.x = f2b(sr*acc[mi][ni][0]); pk.y = f2b(sr*acc[mi][ni][1]);
                    pk.z = f2b(sr*acc[mi][ni][2]); pk.w = f2b(sr*acc[mi][ni][3]);
                    #pragma unroll
                    for (int r=0; r<4; ++r){
                        int lr = mi*16 + rg + r;
                        int dt = wr ? (2*lr + 1) : (2*lr);
                        Trm[ol*TRS + dt] = (&pk.x)[r];
                    }
                }
            }
        }
        __syncthreads();
        { int row = tid >> 3, seg = tid & 7;
          int tb = (t0 >> 5) + (seg >> 1);
          int g0 = (seg & 1) * 2;
          size_t sb = ((size_t)(k*NB + b)*64 + tb) * 8192;
          #pragma unroll
          for (int q = 0; q < 2; ++q){
              const unsigned short* Trm = q ? Bl1 : Bl0;
              U4 v0 = *(const U4*)&Trm[row*TRS + seg*16];
              U4 v1 = *(const U4*)&Trm[row*TRS + seg*16 + 8];
              int o  = (2*h + q)*64 + row;
              *(U4*)&V[sb + swzS(o, g0  )*8] = v0;
              *(U4*)&V[sb + swzS(o, g0+1)*8] = v1;
          }
        }
    }
}

// ---------------- causal Toeplitz conv v9 (proven): 8 waves, 3-buffer depth-2 vmcnt(3) ----------------
__global__ __launch_bounds__(512) void k_conv(const unsigned short* __restrict__ V,
                                              const unsigned short* __restrict__ Tt,
                                              float* __restrict__ y){
    __shared__ __align__(16) unsigned short Abuf[3][4096];
    __shared__ __align__(16) unsigned short Bbuf[3][8192];
    int tid = threadIdx.x, lane = tid & 63, wv = tid >> 6, wr = wv >> 2, wc = wv & 3;
    f32x4 acc[4][4];
    { f32x4 z = {0.f,0.f,0.f,0.f};
      for (int mi=0;mi<4;++mi) for (int ni=0;ni<4;++ni) acc[mi][ni] = z; }

    int b = blockIdx.y, kg = blockIdx.z;
    int px0 = blockIdx.x;
    int px = (px0 & 7)*9 + (px0 >> 3);
    int jx = 0, rem = px;
    #pragma unroll
    for (int j = 0; j < 8; ++j){
        int c = 16 - 2*j;
        if (rem < c){ jx = j; break; }
        rem -= c;
    }
    int tt = 2*jx + rem;
    int t0 = tt*BM;
    int cl = lane & 15, g = lane >> 4;

    int aoff[4], boff[4];
    #pragma unroll
    for (int mi = 0; mi < 4; ++mi) aoff[mi] = swzS(wr*64 + mi*16 + cl, g) << 4;
    #pragma unroll
    for (int ni = 0; ni < 4; ++ni) boff[ni] = swzS(wc*64 + ni*16 + cl, g) << 4;

    const unsigned short* Abase = Tt + (size_t)((kg*KPB*16 + rem)*8) * 4096;
    const unsigned short* Bbase = V  + (((size_t)(kg*KPB*NB + b)*64 + jx*8)) * 8192;

    auto stage = [&](int bi, int step){
        int kk = step >> 3, ts = step & 7;
        const unsigned short* As = Abase + ((size_t)kk*16*8 + ts)*4096 + wv*512;
        const unsigned short* Bs = Bbase + ((size_t)kk*NB*64 + ts)*8192 + wv*1024;
        gl_lds(As + lane*8,       &Abuf[bi][wv*512]);
        gl_lds(Bs + lane*8,       &Bbuf[bi][wv*1024]);
        gl_lds(Bs + 512 + lane*8, &Bbuf[bi][wv*1024 + 512]);
    };

    auto compute = [&](int bi){
        bf16x8 a[4], bb[4];
        #pragma unroll
        for (int mi = 0; mi < 4; ++mi)
            a[mi] = *(const bf16x8*)((const char*)Abuf[bi] + aoff[mi]);
        #pragma unroll
        for (int ni = 0; ni < 4; ++ni)
            bb[ni] = *(const bf16x8*)((const char*)Bbuf[bi] + boff[ni]);
        #pragma unroll
        for (int mi = 0; mi < 4; ++mi)
            #pragma unroll
            for (int ni = 0; ni < 4; ++ni)
                acc[mi][ni] = __builtin_amdgcn_mfma_f32_16x16x32_bf16(a[mi], bb[ni], acc[mi][ni], 0, 0, 0);
    };

    stage(0, 0);
    stage(1, 1);
    int cur = 0;
    for (int t = 0; t < KPB*8 - 1; ++t){
        asm volatile("s_waitcnt vmcnt(3)" ::: "memory");
        __builtin_amdgcn_s_barrier();
        __builtin_amdgcn_sched_barrier(0);
        compute(cur);
        if (t + 2 < KPB*8){
            int nb = cur + 2; if (nb >= 3) nb -= 3;
            stage(nb, t + 2);
        }
        cur = (cur == 2) ? 0 : cur + 1;
    }
    asm volatile("s_waitcnt vmcnt(0)" ::: "memory");
    __builtin_amdgcn_s_barrier();
    __builtin_amdgcn_sched_barrier(0);
    compute(cur);

    int rg = (lane >> 4) * 4;
    #pragma unroll
    for (int mi=0; mi<4; ++mi){
        int tb = t0 + wr*64 + mi*16 + rg;
        #pragma unroll
        for (int ni=0; ni<4; ++ni){
            int o = wc*64 + ni*16 + cl;
            #pragma unroll
            for (int r=0;r<4;++r) atomicAdd(&y[((size_t)b*SLEN + tb + r)*DIM + o], acc[mi][ni][r]);
        }
    }
}

// ---------------- output AR via truncated Q-filter (P=8): gz=7, one tap per block ----------------
__global__ __launch_bounds__(512) void k_qconv(const unsigned short* __restrict__ ybf,
                                               const unsigned short* __restrict__ Q,
                                               float* __restrict__ yh){
    GEMM_PROLOG
    int tt = blockIdx.x, b = blockIdx.y, gz = blockIdx.z;
    int t0 = tt * BM;
    const unsigned short* ysrc = ybf + (size_t)b*SLEN*DIM;
    int p = gz + 1;                        // 1..7
    const unsigned short* Qp = Q + (size_t)p*65536;
    for (int k0 = 0; k0 < 256; k0 += BKK){
        __syncthreads();
        { int row = tid >> 2, sg = tid & 3; int t = t0 + row - p;
          U4 val; val.a=val.b=val.c=val.d=0u;
          if (t >= 0) val = *(const U4*)&ysrc[(size_t)t*DIM + k0 + sg*8];
          *(U4*)&Al[row*PADK + sg*8] = val; }
        #pragma unroll
        for (int s = 0; s < 2; ++s){ int q = tid + s*512; int row = q >> 2, sg = q & 3;
          *(U4*)&Bl[row*PADK + sg*8] = *(const U4*)&Qp[(size_t)row*256 + k0 + sg*8]; }
        __syncthreads();
        mfma_tile(Al, Bl, acc, lane, wr, wc);
    }
    int cl = lane & 15, rg = (lane >> 4) * 4;
    #pragma unroll
    for (int mi=0; mi<4; ++mi){
        int tb = t0 + wr*64 + mi*16 + rg;
        #pragma unroll
        for (int ni=0; ni<4; ++ni){
            int o = wc*64 + ni*16 + cl;
            #pragma unroll
            for (int r=0;r<4;++r) atomicAdd(&yh[((size_t)b*SLEN + tb + r)*DIM + o], acc[mi][ni][r]);
        }
    }
}

// ---------------- fused MLP GEMM1 (f32 A, converts while staging): act = silu(.@w1)*(.@v) ----------------
__global__ __launch_bounds__(512) void k_mlp1f(const float* __restrict__ yhat,
                                               const unsigned short* __restrict__ w1T,
                                               const unsigned short* __restrict__ vT,
                                               unsigned short* __restrict__ act){
    __shared__ unsigned short Al[BM*PADK];
    __shared__ unsigned short Bl0[BN*PADK];
    __shared__ unsigned short Bl1[BN*PADK];
    int tid = threadIdx.x, lane = tid & 63, wv = tid >> 6, wr = wv >> 2, wc = wv & 3;
    f32x4 acc0[4][4], acc1[4][4];
    { f32x4 z = {0.f,0.f,0.f,0.f};
      for (int mi=0;mi<4;++mi) for (int ni=0;ni<4;++ni){ acc0[mi][ni] = z; acc1[mi][ni] = z; } }
    int tt = blockIdx.x, b = blockIdx.y, nt = blockIdx.z;
    int t0 = tt * BM, h0 = nt * 256;
    const float* Asrc = yhat + ((size_t)b*SLEN + t0)*DIM;
    const unsigned short* B0src = w1T + (size_t)h0*DIM;
    const unsigned short* B1src = vT  + (size_t)h0*DIM;
    for (int k0 = 0; k0 < 256; k0 += BKK){
        __syncthreads();
        { int row = tid >> 2, sg = tid & 3;
          const float* src = &Asrc[(size_t)row*DIM + k0 + sg*8];
          float4 f0 = *(const float4*)src, f1 = *(const float4*)(src+4);
          union { U4 v; unsigned short s[8]; } pk;
          pk.s[0]=f2b(f0.x); pk.s[1]=f2b(f0.y); pk.s[2]=f2b(f0.z); pk.s[3]=f2b(f0.w);
          pk.s[4]=f2b(f1.x); pk.s[5]=f2b(f1.y); pk.s[6]=f2b(f1.z); pk.s[7]=f2b(f1.w);
          *(U4*)&Al[row*PADK + sg*8] = pk.v; }
        #pragma unroll
        for (int s = 0; s < 2; ++s){ int q = tid + s*512; int row = q >> 2, sg = q & 3;
          *(U4*)&Bl0[row*PADK + sg*8] = *(const U4*)&B0src[(size_t)row*DIM + k0 + sg*8];
          *(U4*)&Bl1[row*PADK + sg*8] = *(const U4*)&B1src[(size_t)row*DIM + k0 + sg*8]; }
        __syncthreads();
        mfma_tile(Al, Bl0, acc0, lane, wr, wc);
        mfma_tile(Al, Bl1, acc1, lane, wr, wc);
    }
    int cl = lane & 15, rg = (lane >> 4) * 4;
    #pragma unroll
    for (int mi=0; mi<4; ++mi){
        int tb = t0 + wr*64 + mi*16 + rg;
        #pragma unroll
        for (int ni=0; ni<4; ++ni){
            int h = h0 + wc*64 + ni*16 + cl;
            #pragma unroll
            for (int r=0; r<4; ++r){
                float av = acc0[mi][ni][r];
                float sv = av / (1.0f + expf(-av));
                act[(size_t)(b*SLEN + tb + r)*NH + h] = f2b(sv * acc1[mi][ni][r]);
            }
        }
    }
}

// ---------------- MLP GEMM2 (K split z=4): out(=yhat) += act@w2 partial + (z==0)*x ----------------
__global__ __launch_bounds__(512) void k_mlp2(const unsigned short* __restrict__ act,
                                              const unsigned short* __restrict__ w2T,
                                              const float* __restrict__ x,
                                              float* __restrict__ out){
    GEMM_PROLOG
    int tt = blockIdx.x, b = blockIdx.y, ks = blockIdx.z;
    int t0 = tt * BM;
    size_t bt0 = (size_t)b*SLEN + t0;
    for (int k0 = ks*256; k0 < ks*256 + 256; k0 += BKK){
        __syncthreads();
        { int row = tid >> 2, sg = tid & 3;
          *(U4*)&Al[row*PADK + sg*8] = *(const U4*)&act[(bt0 + row)*NH + k0 + sg*8]; }
        #pragma unroll
        for (int s = 0; s < 2; ++s){ int q = tid + s*512; int row = q >> 2, sg = q & 3;
          *(U4*)&Bl[row*PADK + sg*8] = *(const U4*)&w2T[(size_t)row*NH + k0 + sg*8]; }
        __syncthreads();
        mfma_tile(Al, Bl, acc, lane, wr, wc);
    }
    int cl = lane & 15, rg = (lane >> 4) * 4;
    #pragma unroll
    for (int mi=0; mi<4; ++mi){
        #pragma unroll
        for (int ni=0; ni<4; ++ni){
            int o = wc*64 + ni*16 + cl;
            #pragma unroll
            for (int r=0;r<4;++r){
                size_t idx = (bt0 + wr*64 + mi*16 + rg + r)*DIM + o;
                float add = acc[mi][ni][r] + (ks == 0 ? x[idx] : 0.0f);
                atomicAdd(&out[idx], add);
            }
        }
    }
}

// ---------------- host ----------------

extern "C" void kernel_launch(void* const* d_in, const int* in_sizes, int n_in,
                              void* d_out, int out_size, void* d_ws, size_t ws_size,
                              hipStream_t stream) {
    (void)in_sizes; (void)n_in; (void)out_size;
    const float* x     = (const float*)d_in[0];
    const float* sigma = (const float*)d_in[1];
    const float* phi   = (const float*)d_in[2];
    const float* rmsw  = (const float*)d_in[3];
    const float* Mu    = (const float*)d_in[4];
    const float* Mp    = (const float*)d_in[5];
    const float* Mm    = (const float*)d_in[6];
    const float* my    = (const float*)d_in[7];
    const float* w1    = (const float*)d_in[8];
    const float* vv    = (const float*)d_in[9];
    const float* w2    = (const float*)d_in[10];
    float* out = (float*)d_out;

    char* ws = (char*)d_ws;
    size_t off = 0;
    auto alloc = [&](size_t bytes){ size_t o = off; off += (bytes + 255) & ~(size_t)255; return o; };

    size_t o_u    = alloc((size_t)NROW*DIM*2);
    size_t o_T    = alloc((size_t)NKF*16*128*256*2);
    size_t o_MuB  = alloc((size_t)3*65536*2);
    size_t o_MeB  = alloc((size_t)NKF*65536*2);
    size_t o_MoB  = alloc((size_t)NKF*65536*2);
    size_t o_w1T  = alloc((size_t)NH*DIM*2);
    size_t o_vT   = alloc((size_t)NH*DIM*2);
    size_t o_w2T  = alloc((size_t)DIM*NH*2);
    size_t o_pow  = alloc((size_t)5*262144*2);
    size_t o_powT = alloc((size_t)3*262144*2);
    size_t o_Q    = alloc((size_t)8*65536*2);
    size_t o_y    = alloc((size_t)NTOT*4);
    size_t o_ybf  = alloc((size_t)NTOT*2);
    size_t o_V    = alloc(VELEMS*2);
    if (off > ws_size) return;

    unsigned short* u_b  = (unsigned short*)(ws + o_u);
    unsigned short* Tt   = (unsigned short*)(ws + o_T);
    unsigned short* MuB  = (unsigned short*)(ws + o_MuB);
    unsigned short* MeB  = (unsigned short*)(ws + o_MeB);
    unsigned short* MoB  = (unsigned short*)(ws + o_MoB);
    unsigned short* w1T  = (unsigned short*)(ws + o_w1T);
    unsigned short* vT   = (unsigned short*)(ws + o_vT);
    unsigned short* w2T  = (unsigned short*)(ws + o_w2T);
    unsigned short* pw   = (unsigned short*)(ws + o_pow);
    unsigned short* pwTs = (unsigned short*)(ws + o_powT);
    unsigned short* Q    = (unsigned short*)(ws + o_Q);
    float* y             = (float*)(ws + o_y);
    unsigned short* ybf  = (unsigned short*)(ws + o_ybf);
    unsigned short* V    = (unsigned short*)(ws + o_V);
    unsigned short* act  = (unsigned short*)(ws + o_V);     // aliases V (dead after conv)

    // merged prep: rmsnorm + Me/Mo + transposes + buildM + toep
    k_prep<<<dim3(27840), 256, 0, stream>>>(x, rmsw,
                                            (const float4*)Mu, (const float4*)Mp, (const float4*)Mm,
                                            w1, vv, w2, my, phi,
                                            u_b, (S4*)MuB, (S4*)MeB, (S4*)MoB,
                                            w1T, vT, w2T, pw, pwTs, Q, Tt);

    // companion-matrix powers for P=8 taps (p=1..7)
    const int ns[3]   = {1, 2, 4};
    const int cnts[3] = {1, 2, 3};
    for (int s = 0; s < 3; ++s)
        k_pow<<<dim3(4, 2, cnts[s]), 512, 0, stream>>>(pw, pwTs, Q, s, ns[s]);

    // spectral projection (parity-split) + merged ar_u (z == NKF)
    k_proj<<<dim3(16, NB, NKF + 1), 512, 0, stream>>>(u_b, MeB, MoB, MuB, sigma, V, y);

    // single counted-vmcnt conv pass (8-wave v9, proven)
    k_conv<<<dim3(72, NB, KG), 512, 0, stream>>>(V, Tt, y);

    // out = y; ybf = bf16(y)
    k_prep2<<<dim3(NTOT/4/256), 256, 0, stream>>>((const float4*)y, (float4*)out, (S4*)ybf);

    // output AR recurrence (P=8): out += sum_{p=1..7} Q_p y_{t-p}
    k_qconv<<<dim3(16, NB, 7), 512, 0, stream>>>(ybf, Q, out);

    // MLP + residuals: act = silu(out@w1)*(out@v) (stages A from f32 out); out = x + out + act@w2
    k_mlp1f<<<dim3(16, NB, 4), 512, 0, stream>>>(out, w1T, vT, act);
    k_mlp2<<<dim3(16, NB, 4), 512, 0, stream>>>(act, w2T, x, out);
}